// Round 2
// baseline (285.464 us; speedup 1.0000x reference)
//
#include <hip/hip_runtime.h>
#include <limits.h>

#define MAXT 10000
#define BATCH 4096
#define NYB 80            // chunk-row partition of the t axis (grid.y)
#define TCHUNK 16
#define SEGT 1536         // t-steps per prefix segment in scan kernel (256*6)
#define EPT 6             // prefix elems per thread in scan kernel
#define NT2 1024
#define SEG2 10           // 1024*10 = 10240 >= MAXT
#define CUT_ODDS 9.3e-13f // odds <= this  <=>  logit <= -27.70 < -(-log(1e-12)) => no fire possible

#define LOG_GAMMA_C  1.9802627296e-2f   // log(1.02)
#define ALPHA_C     -1.0050335854e-5f   // log(0.99)/1000
#define INIT_LOGW_C -1.3943265329f      // log(0.248)
#define INIT_LOGP_C -6.9077552790f      // log(0.001)
#define EPS_C        1e-12f

// Ping-pong Hillis-Steele scan. BIT-EXACT vs the original in-place ladder:
// round k computes s_k(tid) = s_{k-1}(tid) + (tid>=off ? s_{k-1}(tid-off) : 0.0f)
// -- identical float adds in identical order, just double-buffered so each
// round needs 1 barrier instead of 2. sh must be float[2*n].
__device__ __forceinline__ float block_exscan_tot(float v, float* sh, int tid,
                                                  int n, float* tot) {
    float s = v;
    sh[tid] = s;
    __syncthreads();
    int src = 0;
    for (int off = 1; off < n; off <<= 1) {
        float x = (tid >= off) ? sh[src + tid - off] : 0.0f;
        s += x;
        sh[(src ^ n) + tid] = s;
        __syncthreads();
        src ^= n;
    }
    float excl = (tid > 0) ? sh[src + tid - 1] : 0.0f;
    float t_ = sh[src + n - 1];
    __syncthreads();   // sh reusable after return
    *tot = t_;
    return excl;
}

// shfl-based exclusive scan + total (finalize only — reassociation there
// feeds no thresholded comparison).
__device__ __forceinline__ float block_exscan_tot_fast(float v, float* shw,
                                                       int tid, int nwaves,
                                                       float* tot) {
    float s = v;
    #pragma unroll
    for (int o = 1; o < 64; o <<= 1) {
        float x = __shfl_up(s, o, 64);
        if ((tid & 63) >= o) s += x;
    }
    float sprev = __shfl_up(s, 1, 64);   // inclusive sum through lane-1
    const int wid = tid >> 6, lane = tid & 63;
    if (lane == 63) shw[wid] = s;        // wave total
    __syncthreads();
    float wpre = 0.0f, wtot = 0.0f;
    for (int w = 0; w < nwaves; ++w) {
        float x = shw[w];
        wtot += x;
        if (w < wid) wpre += x;
    }
    __syncthreads();                     // shw reusable after return
    *tot = wtot;
    return (lane == 0) ? wpre : (wpre + sprev);
}

// ---- fused gate-prefix + first-fire scan ---------------------------------
// Every block recomputes the (cheap, t-only) gate sequence itself in LDS,
// then scans its share of u1/u2 chunks. First-fire results go to a single
// ff[BATCH] table via conditional atomicMin (table pre-set to 0xFFFFFFFF).
//
// u2 precheck: fire requires logf(u2+E) > k*logf(u1+E) >= k*logf(1e-12)
// = -27.631*k (for k>=0; for k<0 fire is impossible barring ulp pathology).
// So fire => u2 > expf(-27.631*k) - E. We precompute a CONSERVATIVE
// threshold thr_t = expf(-27.632f*max(k,0)) - 1e-6f (extra-negative log
// constant + 1e-6 margin cover hw-transcendental ulp error on both sides);
// lanes with all 4 u2's <= thr skip the u1 load and both __logf's. Survivors
// evaluate the EXACT original predicate -> fire decisions bit-identical.
__global__ __launch_bounds__(256) void scan_fused(
    const float* __restrict__ acts,
    const float* __restrict__ u1, const float* __restrict__ u2,
    unsigned* __restrict__ ff)      // [BATCH], pre-memset to 0xFF
{
    __shared__ float sh[512];       // ping-pong scan buffer (2*256)
    __shared__ int   swmin[4];
    __shared__ float s_gate[SEGT];
    __shared__ float s_thr[SEGT];

    const int tid = threadIdx.x;
    const int b4  = (blockIdx.x * 256 + tid) * 4;
    const float E = EPS_C;

    float carry_w = INIT_LOGW_C;
    float carry_p = INIT_LOGP_C;
    unsigned f0 = MAXT, f1 = MAXT, f2 = MAXT, f3 = MAXT;

    for (int seg_base = 0; seg_base < MAXT; seg_base += SEGT) {
        // ---- gate prefix for t in [seg_base, seg_base+SEGT) ----
        float fv[EPT], dv[EPT];
        float lsum = 0.0f;
        #pragma unroll
        for (int i = 0; i < EPT; ++i) {
            int t = seg_base + tid * EPT + i;
            if (t < MAXT) {
                float f = expf(acts[t]);
                fv[i] = f;
                dv[i] = LOG_GAMMA_C + logf(1.0f - f);
            } else { fv[i] = 0.0f; dv[i] = 0.0f; }
            lsum += dv[i];
        }
        float dtot;
        float excl = block_exscan_tot(lsum, sh, tid, 256, &dtot);

        float run = carry_w + excl;        // logw BEFORE step t
        float cv[EPT];
        float csum = 0.0f;
        #pragma unroll
        for (int i = 0; i < EPT; ++i) {
            cv[i] = ALPHA_C * fv[i] * expf(run);   // uses OLD logw (ref semantics)
            run += dv[i];
            csum += cv[i];
        }
        float ctot;
        float cexcl = block_exscan_tot(csum, sh, tid, 256, &ctot);

        float logp = carry_p + cexcl;      // logp BEFORE step t
        int localFirst = INT_MAX;
        #pragma unroll
        for (int i = 0; i < EPT; ++i) {
            int t = seg_base + tid * EPT + i;
            float el   = expf(logp);               // -inf -> 0
            float odds = el / (1.0f - el);         // = exp(logit)
            float k    = odds - E;
            s_gate[tid * EPT + i] = k;             // fire iff R < gate
            s_thr [tid * EPT + i] =
                expf(-27.632f * fmaxf(k, 0.0f)) - 1e-6f;   // conservative
            if (localFirst == INT_MAX && odds <= CUT_ODDS) localFirst = t;
            logp += cv[i];
        }
        // segcut: wave-level integer min (exact) + 4-entry LDS exchange
        #pragma unroll
        for (int o = 32; o > 0; o >>= 1)
            localFirst = min(localFirst, __shfl_xor(localFirst, o, 64));
        if ((tid & 63) == 0) swmin[tid >> 6] = localFirst;
        __syncthreads();                   // also covers s_gate/s_thr writes
        const int segcut = min(min(swmin[0], swmin[1]),
                               min(swmin[2], swmin[3]));   // uniform

        // ---- scan this block's chunks within the segment ----
        const int tlimit = min(segcut, MAXT);   // process chunks with tstart < tlimit
        for (int lc = 0; lc < SEGT / TCHUNK; ++lc) {
            const int cg = seg_base / TCHUNK + lc;
            if ((cg % NYB) != (int)blockIdx.y) continue;
            const int tstart = seg_base + lc * TCHUNK;
            if (tstart >= tlimit) break;
            // all 16 u2 loads issued first (MLP), then rare u1 follow-ups
            float4 c[TCHUNK];
            float gv[TCHUNK], tv[TCHUNK];
            #pragma unroll
            for (int q = 0; q < TCHUNK; ++q) {
                const int t = tstart + q;
                c[q]  = *(const float4*)(u2 + (size_t)t * BATCH + b4);
                gv[q] = s_gate[t - seg_base];
                tv[q] = s_thr[t - seg_base];
            }
            #pragma unroll
            for (int q = 0; q < TCHUNK; ++q) {
                if (c[q].x > tv[q] || c[q].y > tv[q] ||
                    c[q].z > tv[q] || c[q].w > tv[q]) {
                    const unsigned t = (unsigned)(tstart + q);
                    const float k = gv[q];
                    const float4 a = *(const float4*)(u1 + (size_t)t * BATCH + b4);
                    // fire iff log(u2+E)/log(u1+E) + E < exp(logit)
                    //      iff log(u2+E) > gate * log(u1+E)   (log(u1+E) < 0)
                    if (__logf(c[q].x + E) > k * __logf(a.x + E)) f0 = min(f0, t);
                    if (__logf(c[q].y + E) > k * __logf(a.y + E)) f1 = min(f1, t);
                    if (__logf(c[q].z + E) > k * __logf(a.z + E)) f2 = min(f2, t);
                    if (__logf(c[q].w + E) > k * __logf(a.w + E)) f3 = min(f3, t);
                }
            }
        }

        if (segcut != INT_MAX) break;      // uniform: no gate can fire beyond
        carry_w += dtot;
        carry_p += ctot;
        __syncthreads();                   // all chunk reads of s_gate done
    }

    // rare conditional atomics replace the 80-row table write
    if (f0 < MAXT) atomicMin(&ff[b4 + 0], f0);
    if (f1 < MAXT) atomicMin(&ff[b4 + 1], f1);
    if (f2 < MAXT) atomicMin(&ff[b4 + 2], f2);
    if (f3 < MAXT) atomicMin(&ff[b4 + 3], f3);
}

// ---- finalize: rpref prefix in LDS, gather ff, mean ----------------------
__global__ __launch_bounds__(NT2) void finalize_kernel(
    const float* __restrict__ acts,
    const unsigned* __restrict__ ff,
    float* __restrict__ out)
{
    __shared__ float  shw[16];
    __shared__ double sdw[16];
    __shared__ float  rp[MAXT + 1];
    const int tid = threadIdx.x;

    // issue the (tiny) ff loads immediately; consumed only after rp is built,
    // so the ~16 KB fetch hides under the prefix computation
    const unsigned fv0 = ff[tid];
    const unsigned fv1 = ff[tid + NT2];
    const unsigned fv2 = ff[tid + 2 * NT2];
    const unsigned fv3 = ff[tid + 3 * NT2];

    const int t0 = tid * SEG2;
    const int n  = (t0 < MAXT) ? min(SEG2, MAXT - t0) : 0;

    float dv[SEG2];
    float lsum = 0.0f;
    for (int i = 0; i < n; ++i) {
        float f = expf(acts[t0 + i]);
        dv[i] = LOG_GAMMA_C + logf(1.0f - f);
        lsum += dv[i];
    }
    float dtot;
    float excl = block_exscan_tot_fast(lsum, shw, tid, NT2 / 64, &dtot);
    float run = INIT_LOGW_C + excl;        // logw BEFORE step t

    float rv[SEG2];
    float rsum = 0.0f;
    for (int i = 0; i < n; ++i) {
        run += dv[i];                      // logw AFTER step t
        rv[i] = expf(run * 1e-3f);         // r_t = exp(new_logw / 1000)
        rsum += rv[i];
    }
    float rtot;
    float rexcl = block_exscan_tot_fast(rsum, shw, tid, NT2 / 64, &rtot);
    float rrun = rexcl;
    for (int i = 0; i < n; ++i) { rp[t0 + i] = rrun; rrun += rv[i]; }
    if (tid == 0) rp[MAXT] = rtot;         // never-fired -> full sum
    __syncthreads();

    double s = 0.0;
    s += (double)rp[min(fv0, (unsigned)MAXT)];
    s += (double)rp[min(fv1, (unsigned)MAXT)];
    s += (double)rp[min(fv2, (unsigned)MAXT)];
    s += (double)rp[min(fv3, (unsigned)MAXT)];

    #pragma unroll
    for (int o = 32; o > 0; o >>= 1) s += __shfl_xor(s, o, 64);
    if ((tid & 63) == 0) sdw[tid >> 6] = s;
    __syncthreads();
    if (tid == 0) {
        double t_ = 0.0;
        for (int w = 0; w < NT2 / 64; ++w) t_ += sdw[w];
        out[0] = (float)(t_ / (double)BATCH);
    }
}

extern "C" void kernel_launch(void* const* d_in, const int* in_sizes, int n_in,
                              void* d_out, int out_size, void* d_ws, size_t ws_size,
                              hipStream_t stream) {
    const float* acts = (const float*)d_in[0];
    const float* u1   = (const float*)d_in[1];
    const float* u2   = (const float*)d_in[2];
    float* out = (float*)d_out;

    unsigned* ff = (unsigned*)d_ws;        // BATCH uints = 16 KB

    // sentinel init (0xFFFFFFFF > MAXT); memset node is graph-capturable
    hipMemsetAsync(ff, 0xFF, BATCH * sizeof(unsigned), stream);

    dim3 grid(BATCH / (256 * 4), NYB);     // (4, 80) = 320 blocks
    scan_fused<<<grid, 256, 0, stream>>>(acts, u1, u2, ff);
    finalize_kernel<<<1, NT2, 0, stream>>>(acts, ff, out);
}

// Round 3
// 278.924 us; speedup vs baseline: 1.0234x; 1.0234x over previous
//
#include <hip/hip_runtime.h>
#include <limits.h>

#define MAXT 10000
#define BATCH 4096
#define NYB 80            // chunk-row partition of the t axis (grid.y)
#define TCHUNK 16
#define SEGT 1536         // t-steps per prefix segment in scan kernel (256*6)
#define EPT 6             // prefix elems per thread in scan kernel
#define NT2 1024
#define SEG2 10           // 1024*10 = 10240 >= MAXT
#define CUT_ODDS 9.3e-13f // odds <= this  <=>  logit <= -27.70 < -(-log(1e-12)) => no fire possible

#define LOG_GAMMA_C  1.9802627296e-2f   // log(1.02)
#define ALPHA_C     -1.0050335854e-5f   // log(0.99)/1000
#define INIT_LOGW_C -1.3943265329f      // log(0.248)
#define INIT_LOGP_C -6.9077552790f      // log(0.001)
#define EPS_C        1e-12f

// Ping-pong Hillis-Steele scan. BIT-EXACT vs the original in-place ladder:
// round k computes s_k(tid) = s_{k-1}(tid) + (tid>=off ? s_{k-1}(tid-off) : 0.0f)
// -- identical float adds in identical order, just double-buffered so each
// round needs 1 barrier instead of 2. sh must be float[2*n].
__device__ __forceinline__ float block_exscan_tot(float v, float* sh, int tid,
                                                  int n, float* tot) {
    float s = v;
    sh[tid] = s;
    __syncthreads();
    int src = 0;
    for (int off = 1; off < n; off <<= 1) {
        float x = (tid >= off) ? sh[src + tid - off] : 0.0f;
        s += x;
        sh[(src ^ n) + tid] = s;
        __syncthreads();
        src ^= n;
    }
    float excl = (tid > 0) ? sh[src + tid - 1] : 0.0f;
    float t_ = sh[src + n - 1];
    __syncthreads();   // sh reusable after return
    *tot = t_;
    return excl;
}

// shfl-based exclusive scan + total (finalize only — reassociation there
// feeds no thresholded comparison).
__device__ __forceinline__ float block_exscan_tot_fast(float v, float* shw,
                                                       int tid, int nwaves,
                                                       float* tot) {
    float s = v;
    #pragma unroll
    for (int o = 1; o < 64; o <<= 1) {
        float x = __shfl_up(s, o, 64);
        if ((tid & 63) >= o) s += x;
    }
    float sprev = __shfl_up(s, 1, 64);   // inclusive sum through lane-1
    const int wid = tid >> 6, lane = tid & 63;
    if (lane == 63) shw[wid] = s;        // wave total
    __syncthreads();
    float wpre = 0.0f, wtot = 0.0f;
    for (int w = 0; w < nwaves; ++w) {
        float x = shw[w];
        wtot += x;
        if (w < wid) wpre += x;
    }
    __syncthreads();                     // shw reusable after return
    *tot = wtot;
    return (lane == 0) ? wpre : (wpre + sprev);
}

// ---- fused gate-prefix + first-fire scan ---------------------------------
// Every block recomputes the (cheap, t-only) gate sequence itself in LDS,
// then scans its share of u1/u2 chunks. First-fire results go to a single
// ff[BATCH] table via conditional atomicMin (table pre-set to 0xFFFFFFFF);
// fires are rare so atomic traffic is trivial.
// NOTE (R2 post-mortem): a u2-value precheck that conditionally skipped the
// u1 load regressed ~2-5us — per-wave the skip probability is ~0 (some lane
// always survives), VGPR footprint doubled (c[16]), and the u1 load gained a
// data dependency on u2. Unconditional interleaved loads pipeline better.
__global__ __launch_bounds__(256) void scan_fused(
    const float* __restrict__ acts,
    const float* __restrict__ u1, const float* __restrict__ u2,
    unsigned* __restrict__ ff)      // [BATCH], pre-memset to 0xFF
{
    __shared__ float sh[512];       // ping-pong scan buffer (2*256)
    __shared__ int   swmin[4];
    __shared__ float s_gate[SEGT];

    const int tid = threadIdx.x;
    const int b4  = (blockIdx.x * 256 + tid) * 4;
    const float E = EPS_C;

    float carry_w = INIT_LOGW_C;
    float carry_p = INIT_LOGP_C;
    unsigned f0 = MAXT, f1 = MAXT, f2 = MAXT, f3 = MAXT;

    for (int seg_base = 0; seg_base < MAXT; seg_base += SEGT) {
        // ---- gate prefix for t in [seg_base, seg_base+SEGT) ----
        float fv[EPT], dv[EPT];
        float lsum = 0.0f;
        #pragma unroll
        for (int i = 0; i < EPT; ++i) {
            int t = seg_base + tid * EPT + i;
            if (t < MAXT) {
                float f = expf(acts[t]);
                fv[i] = f;
                dv[i] = LOG_GAMMA_C + logf(1.0f - f);
            } else { fv[i] = 0.0f; dv[i] = 0.0f; }
            lsum += dv[i];
        }
        float dtot;
        float excl = block_exscan_tot(lsum, sh, tid, 256, &dtot);

        float run = carry_w + excl;        // logw BEFORE step t
        float cv[EPT];
        float csum = 0.0f;
        #pragma unroll
        for (int i = 0; i < EPT; ++i) {
            cv[i] = ALPHA_C * fv[i] * expf(run);   // uses OLD logw (ref semantics)
            run += dv[i];
            csum += cv[i];
        }
        float ctot;
        float cexcl = block_exscan_tot(csum, sh, tid, 256, &ctot);

        float logp = carry_p + cexcl;      // logp BEFORE step t
        int localFirst = INT_MAX;
        #pragma unroll
        for (int i = 0; i < EPT; ++i) {
            int t = seg_base + tid * EPT + i;
            float el   = expf(logp);               // -inf -> 0
            float odds = el / (1.0f - el);         // = exp(logit)
            s_gate[tid * EPT + i] = odds - E;      // fire iff R < gate
            if (localFirst == INT_MAX && odds <= CUT_ODDS) localFirst = t;
            logp += cv[i];
        }
        // segcut: wave-level integer min (exact) + 4-entry LDS exchange
        #pragma unroll
        for (int o = 32; o > 0; o >>= 1)
            localFirst = min(localFirst, __shfl_xor(localFirst, o, 64));
        if ((tid & 63) == 0) swmin[tid >> 6] = localFirst;
        __syncthreads();                   // also covers s_gate writes
        const int segcut = min(min(swmin[0], swmin[1]),
                               min(swmin[2], swmin[3]));   // uniform

        // ---- scan this block's chunks within the segment ----
        const int tlimit = min(segcut, MAXT);   // process chunks with tstart < tlimit
        for (int lc = 0; lc < SEGT / TCHUNK; ++lc) {
            const int cg = seg_base / TCHUNK + lc;
            if ((cg % NYB) != (int)blockIdx.y) continue;
            const int tstart = seg_base + lc * TCHUNK;
            if (tstart >= tlimit) break;
            // fixed-trip 16 steps: steps past tlimit use real gate values
            // (cannot fire mathematically) -> fully unrollable, loads pipeline
            #pragma unroll
            for (int g = 0; g < TCHUNK / 4; ++g) {
                float4 a[4], c[4];
                float gv[4];
                #pragma unroll
                for (int j = 0; j < 4; ++j) {
                    const int t = tstart + g * 4 + j;
                    a[j]  = *(const float4*)(u1 + (size_t)t * BATCH + b4);
                    c[j]  = *(const float4*)(u2 + (size_t)t * BATCH + b4);
                    gv[j] = s_gate[t - seg_base];
                }
                #pragma unroll
                for (int j = 0; j < 4; ++j) {
                    const unsigned t = (unsigned)(tstart + g * 4 + j);
                    const float k = gv[j];
                    // fire iff log(u2+E)/log(u1+E) + E < exp(logit)
                    //      iff log(u2+E) > gate * log(u1+E)   (log(u1+E) < 0)
                    if (__logf(c[j].x + E) > k * __logf(a[j].x + E)) f0 = min(f0, t);
                    if (__logf(c[j].y + E) > k * __logf(a[j].y + E)) f1 = min(f1, t);
                    if (__logf(c[j].z + E) > k * __logf(a[j].z + E)) f2 = min(f2, t);
                    if (__logf(c[j].w + E) > k * __logf(a[j].w + E)) f3 = min(f3, t);
                }
            }
        }

        if (segcut != INT_MAX) break;      // uniform: no gate can fire beyond
        carry_w += dtot;
        carry_p += ctot;
        __syncthreads();                   // all chunk reads of s_gate done
    }

    // rare conditional atomics replace a per-row table write
    if (f0 < MAXT) atomicMin(&ff[b4 + 0], f0);
    if (f1 < MAXT) atomicMin(&ff[b4 + 1], f1);
    if (f2 < MAXT) atomicMin(&ff[b4 + 2], f2);
    if (f3 < MAXT) atomicMin(&ff[b4 + 3], f3);
}

// ---- finalize: rpref prefix in LDS, gather ff, mean ----------------------
__global__ __launch_bounds__(NT2) void finalize_kernel(
    const float* __restrict__ acts,
    const unsigned* __restrict__ ff,
    float* __restrict__ out)
{
    __shared__ float  shw[16];
    __shared__ double sdw[16];
    __shared__ float  rp[MAXT + 1];
    const int tid = threadIdx.x;

    // issue the (tiny) ff loads immediately; consumed only after rp is built,
    // so the ~16 KB fetch hides under the prefix computation
    const unsigned fv0 = ff[tid];
    const unsigned fv1 = ff[tid + NT2];
    const unsigned fv2 = ff[tid + 2 * NT2];
    const unsigned fv3 = ff[tid + 3 * NT2];

    const int t0 = tid * SEG2;
    const int n  = (t0 < MAXT) ? min(SEG2, MAXT - t0) : 0;

    float dv[SEG2];
    float lsum = 0.0f;
    for (int i = 0; i < n; ++i) {
        float f = expf(acts[t0 + i]);
        dv[i] = LOG_GAMMA_C + logf(1.0f - f);
        lsum += dv[i];
    }
    float dtot;
    float excl = block_exscan_tot_fast(lsum, shw, tid, NT2 / 64, &dtot);
    float run = INIT_LOGW_C + excl;        // logw BEFORE step t

    float rv[SEG2];
    float rsum = 0.0f;
    for (int i = 0; i < n; ++i) {
        run += dv[i];                      // logw AFTER step t
        rv[i] = expf(run * 1e-3f);         // r_t = exp(new_logw / 1000)
        rsum += rv[i];
    }
    float rtot;
    float rexcl = block_exscan_tot_fast(rsum, shw, tid, NT2 / 64, &rtot);
    float rrun = rexcl;
    for (int i = 0; i < n; ++i) { rp[t0 + i] = rrun; rrun += rv[i]; }
    if (tid == 0) rp[MAXT] = rtot;         // never-fired -> full sum
    __syncthreads();

    double s = 0.0;
    s += (double)rp[min(fv0, (unsigned)MAXT)];
    s += (double)rp[min(fv1, (unsigned)MAXT)];
    s += (double)rp[min(fv2, (unsigned)MAXT)];
    s += (double)rp[min(fv3, (unsigned)MAXT)];

    #pragma unroll
    for (int o = 32; o > 0; o >>= 1) s += __shfl_xor(s, o, 64);
    if ((tid & 63) == 0) sdw[tid >> 6] = s;
    __syncthreads();
    if (tid == 0) {
        double t_ = 0.0;
        for (int w = 0; w < NT2 / 64; ++w) t_ += sdw[w];
        out[0] = (float)(t_ / (double)BATCH);
    }
}

extern "C" void kernel_launch(void* const* d_in, const int* in_sizes, int n_in,
                              void* d_out, int out_size, void* d_ws, size_t ws_size,
                              hipStream_t stream) {
    const float* acts = (const float*)d_in[0];
    const float* u1   = (const float*)d_in[1];
    const float* u2   = (const float*)d_in[2];
    float* out = (float*)d_out;

    unsigned* ff = (unsigned*)d_ws;        // BATCH uints = 16 KB

    // sentinel init (0xFFFFFFFF > MAXT); memset node is graph-capturable
    hipMemsetAsync(ff, 0xFF, BATCH * sizeof(unsigned), stream);

    dim3 grid(BATCH / (256 * 4), NYB);     // (4, 80) = 320 blocks
    scan_fused<<<grid, 256, 0, stream>>>(acts, u1, u2, ff);
    finalize_kernel<<<1, NT2, 0, stream>>>(acts, ff, out);
}